// Round 1
// baseline (483.274 us; speedup 1.0000x reference)
//
#include <hip/hip_runtime.h>
#include <hip/hip_bf16.h>
#include <stdint.h>

#define N_ROWS 8192
#define IN_DIM 4096
#define OUT_DIM 4096
#define EPS 1e-5f

typedef __attribute__((ext_vector_type(8))) short bf16x8;
typedef __attribute__((ext_vector_type(4))) float f32x4;
typedef __attribute__((ext_vector_type(8))) unsigned short u16x8;

typedef const __attribute__((address_space(1))) void gbl_void_t;
typedef __attribute__((address_space(3))) void lds_void_t;

__device__ __forceinline__ void gload_lds16(const void* g, void* l) {
    __builtin_amdgcn_global_load_lds((gbl_void_t*)g, (lds_void_t*)l, 16, 0, 0);
}

// ---------------- kernel 1: x_bf16 = bf16(input * factor) ----------------
__global__ __launch_bounds__(256) void scale_cast_kernel(
    const float* __restrict__ input, const float* __restrict__ factor,
    unsigned short* __restrict__ xbf)
{
    long long idx = (long long)blockIdx.x * blockDim.x + threadIdx.x;
    long long base = idx * 8;
    if (base >= (long long)N_ROWS * IN_DIM) return;
    int col = (int)(base & (IN_DIM - 1));     // multiple of 8
    float4 a0 = *(const float4*)(input + base);
    float4 a1 = *(const float4*)(input + base + 4);
    float4 f0 = *(const float4*)(factor + col);
    float4 f1 = *(const float4*)(factor + col + 4);
    float v[8] = {a0.x*f0.x, a0.y*f0.y, a0.z*f0.z, a0.w*f0.w,
                  a1.x*f1.x, a1.y*f1.y, a1.z*f1.z, a1.w*f1.w};
    u16x8 r;
    #pragma unroll
    for (int j = 0; j < 8; ++j) {
        union { float f; unsigned u; } c; c.f = v[j];
        unsigned lsb = (c.u >> 16) & 1u;
        unsigned rnd = c.u + 0x7FFFu + lsb;   // round-to-nearest-even bf16
        r[j] = (unsigned short)(rnd >> 16);
    }
    *(u16x8*)(xbf + base) = r;
}

// ---------------- kernel 2: unpack packed ±1 weights to bf16 ----------------
__global__ __launch_bounds__(256) void unpack_kernel(
    const int* __restrict__ wpacked, unsigned short* __restrict__ wbf)
{
    int idx = blockIdx.x * blockDim.x + threadIdx.x;  // packed-byte index
    if (idx >= OUT_DIM * (IN_DIM / 8)) return;
    unsigned byte = (unsigned)wpacked[idx];
    u16x8 r;
    #pragma unroll
    for (int b = 0; b < 8; ++b) {
        unsigned bit = (byte >> b) & 1u;
        r[b] = (unsigned short)(0x3F80u | (bit << 15));  // +1.0 / -1.0 bf16
    }
    *(u16x8*)(wbf + (long long)idx * 8) = r;
}

// ---------------- kernel 3: bf16 GEMM (m97 structure) ----------------
// C[m][o] = sum_k A[m][k] * B[o][k], scaled by wscale[o]. A:[8192][4096], B:[4096][4096]
#define BM 128
#define BN 128
#define BK 64

__global__ __launch_bounds__(256) void gemm_kernel(
    const unsigned short* __restrict__ A, const unsigned short* __restrict__ B,
    const float* __restrict__ wscale, float* __restrict__ C)
{
    __shared__ unsigned short Asm[BM * BK];
    __shared__ unsigned short Bsm[BN * BK];

    // bijective XCD swizzle (nwg = 2048, divisible by 8)
    int nwg = gridDim.x;
    int bid = blockIdx.x;
    int swz = (bid & 7) * (nwg >> 3) + (bid >> 3);
    int bn = swz & ((OUT_DIM / BN) - 1);   // 32 panels
    int bm = swz / (OUT_DIM / BN);
    int m0 = bm * BM, n0 = bn * BN;

    int tid = threadIdx.x;
    int lane = tid & 63;
    int w = tid >> 6;           // wave 0..3
    int wm = w >> 1, wn = w & 1;

    // staging: per wave 4 chunks of 1024B per tile; 1024B = 8 rows of 128B
    int srow = w * 32 + (lane >> 3);
    int scol = (lane & 7) * 8;

    f32x4 acc[4][4] = {};

    for (int k0 = 0; k0 < IN_DIM; k0 += BK) {
        #pragma unroll
        for (int q = 0; q < 4; ++q) {
            const unsigned short* ga = A + (long long)(m0 + srow + q * 8) * IN_DIM + k0 + scol;
            gload_lds16(ga, Asm + w * 2048 + q * 512);   // wave-uniform LDS base
            const unsigned short* gb = B + (long long)(n0 + srow + q * 8) * IN_DIM + k0 + scol;
            gload_lds16(gb, Bsm + w * 2048 + q * 512);
        }
        __syncthreads();   // drains vmcnt(0) -> staged tiles visible

        #pragma unroll
        for (int ks = 0; ks < 2; ++ks) {
            int kc = ks * 32 + (lane >> 4) * 8;
            bf16x8 af[4], bfr[4];
            #pragma unroll
            for (int t = 0; t < 4; ++t) {
                af[t]  = *(const bf16x8*)(Asm + (wm * 64 + t * 16 + (lane & 15)) * BK + kc);
                bfr[t] = *(const bf16x8*)(Bsm + (wn * 64 + t * 16 + (lane & 15)) * BK + kc);
            }
            #pragma unroll
            for (int i = 0; i < 4; ++i)
                #pragma unroll
                for (int j = 0; j < 4; ++j)
                    acc[i][j] = __builtin_amdgcn_mfma_f32_16x16x32_bf16(af[i], bfr[j], acc[i][j], 0, 0, 0);
        }
        __syncthreads();
    }

    // epilogue: C[row][col] = acc * wscale[col]
    int crow = m0 + wm * 64;
    int ccol = n0 + wn * 64;
    #pragma unroll
    for (int j = 0; j < 4; ++j) {
        int col = ccol + j * 16 + (lane & 15);
        float ws = wscale[col];
        #pragma unroll
        for (int i = 0; i < 4; ++i) {
            int row0 = crow + i * 16 + (lane >> 4) * 4;
            #pragma unroll
            for (int r = 0; r < 4; ++r)
                C[(long long)(row0 + r) * OUT_DIM + col] = acc[i][j][r] * ws;
        }
    }
}

// ---------------- kernel 4: in-place LayerNorm over OUT + bias ----------------
__global__ __launch_bounds__(256) void ln_kernel(
    float* __restrict__ out, const float* __restrict__ bias)
{
    int row = blockIdx.x;
    int tid = threadIdx.x;
    float* p = out + (long long)row * OUT_DIM;

    float4 v[4];
    float sum = 0.f, sumsq = 0.f;
    #pragma unroll
    for (int q = 0; q < 4; ++q) {
        v[q] = *(const float4*)(p + (q * 256 + tid) * 4);
        sum   += v[q].x + v[q].y + v[q].z + v[q].w;
        sumsq += v[q].x*v[q].x + v[q].y*v[q].y + v[q].z*v[q].z + v[q].w*v[q].w;
    }
    #pragma unroll
    for (int off = 32; off > 0; off >>= 1) {
        sum   += __shfl_down(sum, off);
        sumsq += __shfl_down(sumsq, off);
    }
    __shared__ float ssum[4], ssq[4];
    if ((tid & 63) == 0) { ssum[tid >> 6] = sum; ssq[tid >> 6] = sumsq; }
    __syncthreads();
    sum   = ssum[0] + ssum[1] + ssum[2] + ssum[3];
    sumsq = ssq[0] + ssq[1] + ssq[2] + ssq[3];
    float mean = sum * (1.0f / OUT_DIM);
    float var  = sumsq * (1.0f / OUT_DIM) - mean * mean;
    float inv  = rsqrtf(var + EPS);

    #pragma unroll
    for (int q = 0; q < 4; ++q) {
        int c = (q * 256 + tid) * 4;
        float4 b = *(const float4*)(bias + c);
        float4 r;
        r.x = (v[q].x - mean) * inv + b.x;
        r.y = (v[q].y - mean) * inv + b.y;
        r.z = (v[q].z - mean) * inv + b.z;
        r.w = (v[q].w - mean) * inv + b.w;
        *(float4*)(p + c) = r;
    }
}

extern "C" void kernel_launch(void* const* d_in, const int* in_sizes, int n_in,
                              void* d_out, int out_size, void* d_ws, size_t ws_size,
                              hipStream_t stream) {
    const float* input   = (const float*)d_in[0];
    const int*   weight  = (const int*)d_in[1];
    const float* wscale  = (const float*)d_in[2];
    const float* factor  = (const float*)d_in[3];
    const float* bias    = (const float*)d_in[4];
    float* out = (float*)d_out;

    unsigned short* xbf = (unsigned short*)d_ws;                               // 64 MiB
    unsigned short* wbf = (unsigned short*)d_ws + (size_t)N_ROWS * IN_DIM;     // 32 MiB

    // 1. x_bf16 = bf16(input * factor)
    {
        long long total = (long long)N_ROWS * IN_DIM / 8;
        int blocks = (int)((total + 255) / 256);
        scale_cast_kernel<<<blocks, 256, 0, stream>>>(input, factor, xbf);
    }
    // 2. unpack weights
    {
        int total = OUT_DIM * (IN_DIM / 8);
        unpack_kernel<<<(total + 255) / 256, 256, 0, stream>>>(weight, wbf);
    }
    // 3. GEMM + weight_scale
    {
        int grid = (N_ROWS / BM) * (OUT_DIM / BN);   // 2048
        gemm_kernel<<<grid, 256, 0, stream>>>(xbf, wbf, wscale, out);
    }
    // 4. LayerNorm + bias (in-place)
    ln_kernel<<<N_ROWS, 256, 0, stream>>>(out, bias);
}

// Round 2
// 290.158 us; speedup vs baseline: 1.6656x; 1.6656x over previous
//
#include <hip/hip_runtime.h>
#include <hip/hip_bf16.h>
#include <stdint.h>

#define N_ROWS 8192
#define IN_DIM 4096
#define OUT_DIM 4096
#define EPS 1e-5f

typedef unsigned short u16;
typedef __attribute__((ext_vector_type(8))) short bf16x8;
typedef __attribute__((ext_vector_type(4))) float f32x4;
typedef __attribute__((ext_vector_type(8))) unsigned short u16x8;

typedef const __attribute__((address_space(1))) void gbl_void_t;
typedef __attribute__((address_space(3))) void lds_void_t;

__device__ __forceinline__ void gload_lds16(const void* g, void* l) {
    __builtin_amdgcn_global_load_lds((gbl_void_t*)g, (lds_void_t*)l, 16, 0, 0);
}

// ---------------- kernel 1: x_bf16 = bf16(input * factor) ----------------
__global__ __launch_bounds__(256) void scale_cast_kernel(
    const float* __restrict__ input, const float* __restrict__ factor,
    unsigned short* __restrict__ xbf)
{
    long long idx = (long long)blockIdx.x * blockDim.x + threadIdx.x;
    long long base = idx * 8;
    if (base >= (long long)N_ROWS * IN_DIM) return;
    int col = (int)(base & (IN_DIM - 1));
    float4 a0 = *(const float4*)(input + base);
    float4 a1 = *(const float4*)(input + base + 4);
    float4 f0 = *(const float4*)(factor + col);
    float4 f1 = *(const float4*)(factor + col + 4);
    float v[8] = {a0.x*f0.x, a0.y*f0.y, a0.z*f0.z, a0.w*f0.w,
                  a1.x*f1.x, a1.y*f1.y, a1.z*f1.z, a1.w*f1.w};
    u16x8 r;
    #pragma unroll
    for (int j = 0; j < 8; ++j) {
        union { float f; unsigned u; } c; c.f = v[j];
        unsigned lsb = (c.u >> 16) & 1u;
        unsigned rnd = c.u + 0x7FFFu + lsb;
        r[j] = (unsigned short)(rnd >> 16);
    }
    *(u16x8*)(xbf + base) = r;
}

// ---------------- kernel 2: unpack packed ±1 weights to bf16 ----------------
__global__ __launch_bounds__(256) void unpack_kernel(
    const int* __restrict__ wpacked, unsigned short* __restrict__ wbf)
{
    int idx = blockIdx.x * blockDim.x + threadIdx.x;
    if (idx >= OUT_DIM * (IN_DIM / 8)) return;
    unsigned byte = (unsigned)wpacked[idx];
    u16x8 r;
    #pragma unroll
    for (int b = 0; b < 8; ++b) {
        unsigned bit = (byte >> b) & 1u;
        r[b] = (unsigned short)(0x3F80u | (bit << 15));
    }
    *(u16x8*)(wbf + (long long)idx * 8) = r;
}

// ---------------- kernel 3: 256x256 8-phase bf16 GEMM (T2+T3+T4+T5+T1) ----------------
// C[m][o] = (sum_k A[m][k]*B[o][k]) * wscale[o]
// 512 thr = 8 waves (2M x 4N); wave tile 128x64; BK=64; LDS 128KiB dbuf.
// LDS swizzle: segment (row, s) at slot s^(row&7); staged via inverse-swizzled
// global source (gload_lds writes linearly), read with same XOR.

template<int MLO, int MHI>
__device__ __forceinline__ void read_a(bf16x8 (&af)[8][2], const u16* ap, int lane) {
    int rb = (lane & 15) << 6, g = lane >> 4, x = lane & 7;
    #pragma unroll
    for (int m = MLO; m < MHI; ++m)
        #pragma unroll
        for (int ks = 0; ks < 2; ++ks)
            af[m][ks] = *(const bf16x8*)(ap + m*1024 + rb + (((ks*4+g)^x) << 3));
}
template<int NLO, int NHI>
__device__ __forceinline__ void read_b(bf16x8 (&bfr)[4][2], const u16* bp, int lane, int rowoff) {
    int rb = rowoff + ((lane & 15) << 6), g = lane >> 4, x = lane & 7;
    #pragma unroll
    for (int n = NLO; n < NHI; ++n)
        #pragma unroll
        for (int ks = 0; ks < 2; ++ks)
            bfr[n][ks] = *(const bf16x8*)(bp + n*1024 + rb + (((ks*4+g)^x) << 3));
}
template<int QM, int QN>
__device__ __forceinline__ void mfma_quad(f32x4 (&acc)[8][4], bf16x8 (&af)[8][2], bf16x8 (&bfr)[4][2]) {
    #pragma unroll
    for (int i = 0; i < 4; ++i)
        #pragma unroll
        for (int j = 0; j < 2; ++j)
            #pragma unroll
            for (int ks = 0; ks < 2; ++ks)
                acc[QM*4+i][QN*2+j] = __builtin_amdgcn_mfma_f32_16x16x32_bf16(
                    af[QM*4+i][ks], bfr[QN*2+j][ks], acc[QM*4+i][QN*2+j], 0, 0, 0);
}

__device__ __forceinline__ void stage_half(const u16* g, u16* l, int w) {
    // wave w stages chunks 2w, 2w+1 (8 rows x 128B each) of one 128x64 half-tile
    gload_lds16(g + (size_t)(w*16)   * IN_DIM, l + w*1024);
    gload_lds16(g + (size_t)(w*16+8) * IN_DIM, l + w*1024 + 512);
}

#define SYNC_PRE() do { __builtin_amdgcn_s_barrier(); \
    asm volatile("s_waitcnt lgkmcnt(0)" ::: "memory"); \
    __builtin_amdgcn_s_setprio(1); } while(0)
#define SYNC_POST() do { __builtin_amdgcn_s_setprio(0); \
    __builtin_amdgcn_s_barrier(); } while(0)
#define VMCNT(n) asm volatile("s_waitcnt vmcnt(" #n ")" ::: "memory")

__global__ __launch_bounds__(512, 2) void gemm_kernel(
    const u16* __restrict__ A, const u16* __restrict__ B,
    const float* __restrict__ wscale, float* __restrict__ C)
{
    __shared__ u16 lds[65536];   // 128 KiB: [buf][A/B][half][128*64]

    int nwg = gridDim.x;   // 512, divisible by 8
    int bid = blockIdx.x;
    int swz = (bid & 7) * (nwg >> 3) + (bid >> 3);   // bijective XCD swizzle
    int bn = swz & 15;
    int bm = swz >> 4;
    int m0 = bm * 256, n0 = bn * 256;

    int tid = threadIdx.x;
    int lane = tid & 63;
    int w = tid >> 6;
    int wm = w >> 2, wn = w & 3;

    // staging per-lane global base (inverse-swizzled source, m173/m201 pattern)
    int srow = lane >> 3, sslot = (lane & 7) ^ srow;
    const u16* Ag = A + (size_t)(m0 + srow) * IN_DIM + sslot * 8;
    const u16* Bg = B + (size_t)(n0 + srow) * IN_DIM + sslot * 8;
    const size_t H = (size_t)128 * IN_DIM;

    u16* L = lds;
    // LDS region offsets (u16): buf0: A0=0 A1=8192 B0=16384 B1=24576; buf1: +32768
    const u16* aprd0 = lds + wm * 8192;
    const u16* aprd1 = lds + 32768 + wm * 8192;
    const u16* bprd0 = lds + 16384 + (wn >> 1) * 8192;
    const u16* bprd1 = lds + 49152 + (wn >> 1) * 8192;
    int brow = (wn & 1) * 4096;

    bf16x8 af[8][2], bfr[4][2];
    f32x4 acc[8][4] = {};

    // prologue: K0 -> buf0 (A0,A1,B0,B1); K1 -> buf1 (A0,A1,B0); 7 half-tiles
    stage_half(Ag,          L + 0,     w);
    stage_half(Ag + H,      L + 8192,  w);
    stage_half(Bg,          L + 16384, w);
    stage_half(Bg + H,      L + 24576, w);
    VMCNT(4);
    stage_half(Ag + 64,     L + 32768, w);
    stage_half(Ag + H + 64, L + 40960, w);
    stage_half(Bg + 64,     L + 49152, w);
    VMCNT(6);
    __builtin_amdgcn_s_barrier();

    for (int it = 0; it < 31; ++it) {
        int s1 = (2*it + 1) * 64, s2 = (2*it + 2) * 64, s3 = (2*it + 3) * 64;
        // P1: read A(T0) (wm0: all 8, deadline P2-stage; wm1: lo 4) + B qn0; stage B1(K2it+1)
        if (wm == 0) read_a<0,8>(af, aprd0, lane); else read_a<0,4>(af, aprd0, lane);
        read_b<0,2>(bfr, bprd0, lane, brow);
        stage_half(Bg + H + s1, L + 57344, w);
        SYNC_PRE(); mfma_quad<0,0>(acc, af, bfr); SYNC_POST();
        // P2: wm1 hi A; B qn1; stage A0(K2it+2)
        if (wm == 1) read_a<4,8>(af, aprd0, lane);
        read_b<2,4>(bfr, bprd0, lane, brow);
        stage_half(Ag + s2, L + 0, w);
        SYNC_PRE(); mfma_quad<0,1>(acc, af, bfr); SYNC_POST();
        // P3: stage A1(K2it+2)
        stage_half(Ag + H + s2, L + 8192, w);
        SYNC_PRE(); mfma_quad<1,0>(acc, af, bfr); SYNC_POST();
        // P4: stage B0(K2it+2); counted vmcnt -> T1 fully landed, 3 half-tiles in flight
        stage_half(Bg + s2, L + 16384, w);
        VMCNT(6);
        SYNC_PRE(); mfma_quad<1,1>(acc, af, bfr); SYNC_POST();
        // P5: read T1 (buf1); stage B1(K2it+2)
        if (wm == 0) read_a<0,8>(af, aprd1, lane); else read_a<0,4>(af, aprd1, lane);
        read_b<0,2>(bfr, bprd1, lane, brow);
        stage_half(Bg + H + s2, L + 24576, w);
        SYNC_PRE(); mfma_quad<0,0>(acc, af, bfr); SYNC_POST();
        // P6: stage A0(K2it+3)
        if (wm == 1) read_a<4,8>(af, aprd1, lane);
        read_b<2,4>(bfr, bprd1, lane, brow);
        stage_half(Ag + s3, L + 32768, w);
        SYNC_PRE(); mfma_quad<0,1>(acc, af, bfr); SYNC_POST();
        // P7: stage A1(K2it+3)
        stage_half(Ag + H + s3, L + 40960, w);
        SYNC_PRE(); mfma_quad<1,0>(acc, af, bfr); SYNC_POST();
        // P8: stage B0(K2it+3); counted vmcnt
        stage_half(Bg + s3, L + 49152, w);
        VMCNT(6);
        SYNC_PRE(); mfma_quad<1,1>(acc, af, bfr); SYNC_POST();
    }

    // peeled tail: T0=K62 (buf0), T1=K63 (buf1); only B1(K63) left to stage
    {
        const int s1 = 63 * 64;
        if (wm == 0) read_a<0,8>(af, aprd0, lane); else read_a<0,4>(af, aprd0, lane);
        read_b<0,2>(bfr, bprd0, lane, brow);
        stage_half(Bg + H + s1, L + 57344, w);
        SYNC_PRE(); mfma_quad<0,0>(acc, af, bfr); SYNC_POST();

        if (wm == 1) read_a<4,8>(af, aprd0, lane);
        read_b<2,4>(bfr, bprd0, lane, brow);
        SYNC_PRE(); mfma_quad<0,1>(acc, af, bfr); SYNC_POST();

        SYNC_PRE(); mfma_quad<1,0>(acc, af, bfr); SYNC_POST();

        VMCNT(0);   // drain: all of K63 landed
        SYNC_PRE(); mfma_quad<1,1>(acc, af, bfr); SYNC_POST();

        if (wm == 0) read_a<0,8>(af, aprd1, lane); else read_a<0,4>(af, aprd1, lane);
        read_b<0,2>(bfr, bprd1, lane, brow);
        SYNC_PRE(); mfma_quad<0,0>(acc, af, bfr); SYNC_POST();

        if (wm == 1) read_a<4,8>(af, aprd1, lane);
        read_b<2,4>(bfr, bprd1, lane, brow);
        SYNC_PRE(); mfma_quad<0,1>(acc, af, bfr); SYNC_POST();

        SYNC_PRE(); mfma_quad<1,0>(acc, af, bfr); SYNC_POST();

        SYNC_PRE(); mfma_quad<1,1>(acc, af, bfr);
        __builtin_amdgcn_s_setprio(0);
    }

    // epilogue: scaled C-write
    int crow = m0 + wm * 128;
    int ccol = n0 + wn * 64;
    #pragma unroll
    for (int n = 0; n < 4; ++n) {
        int col = ccol + n * 16 + (lane & 15);
        float ws = wscale[col];
        #pragma unroll
        for (int m = 0; m < 8; ++m) {
            int row0 = crow + m * 16 + (lane >> 4) * 4;
            #pragma unroll
            for (int r = 0; r < 4; ++r)
                C[(size_t)(row0 + r) * OUT_DIM + col] = acc[m][n][r] * ws;
        }
    }
}

// ---------------- kernel 4: in-place LayerNorm over OUT + bias ----------------
__global__ __launch_bounds__(256) void ln_kernel(
    float* __restrict__ out, const float* __restrict__ bias)
{
    int row = blockIdx.x;
    int tid = threadIdx.x;
    float* p = out + (long long)row * OUT_DIM;

    float4 v[4];
    float sum = 0.f, sumsq = 0.f;
    #pragma unroll
    for (int q = 0; q < 4; ++q) {
        v[q] = *(const float4*)(p + (q * 256 + tid) * 4);
        sum   += v[q].x + v[q].y + v[q].z + v[q].w;
        sumsq += v[q].x*v[q].x + v[q].y*v[q].y + v[q].z*v[q].z + v[q].w*v[q].w;
    }
    #pragma unroll
    for (int off = 32; off > 0; off >>= 1) {
        sum   += __shfl_down(sum, off);
        sumsq += __shfl_down(sumsq, off);
    }
    __shared__ float ssum[4], ssq[4];
    if ((tid & 63) == 0) { ssum[tid >> 6] = sum; ssq[tid >> 6] = sumsq; }
    __syncthreads();
    sum   = ssum[0] + ssum[1] + ssum[2] + ssum[3];
    sumsq = ssq[0] + ssq[1] + ssq[2] + ssq[3];
    float mean = sum * (1.0f / OUT_DIM);
    float var  = sumsq * (1.0f / OUT_DIM) - mean * mean;
    float inv  = rsqrtf(var + EPS);

    #pragma unroll
    for (int q = 0; q < 4; ++q) {
        int c = (q * 256 + tid) * 4;
        float4 b = *(const float4*)(bias + c);
        float4 r;
        r.x = (v[q].x - mean) * inv + b.x;
        r.y = (v[q].y - mean) * inv + b.y;
        r.z = (v[q].z - mean) * inv + b.z;
        r.w = (v[q].w - mean) * inv + b.w;
        *(float4*)(p + c) = r;
    }
}

extern "C" void kernel_launch(void* const* d_in, const int* in_sizes, int n_in,
                              void* d_out, int out_size, void* d_ws, size_t ws_size,
                              hipStream_t stream) {
    const float* input   = (const float*)d_in[0];
    const int*   weight  = (const int*)d_in[1];
    const float* wscale  = (const float*)d_in[2];
    const float* factor  = (const float*)d_in[3];
    const float* bias    = (const float*)d_in[4];
    float* out = (float*)d_out;

    unsigned short* xbf = (unsigned short*)d_ws;
    unsigned short* wbf = (unsigned short*)d_ws + (size_t)N_ROWS * IN_DIM;

    {
        long long total = (long long)N_ROWS * IN_DIM / 8;
        int blocks = (int)((total + 255) / 256);
        scale_cast_kernel<<<blocks, 256, 0, stream>>>(input, factor, xbf);
    }
    {
        int total = OUT_DIM * (IN_DIM / 8);
        unpack_kernel<<<(total + 255) / 256, 256, 0, stream>>>(weight, wbf);
    }
    {
        int grid = (N_ROWS / 256) * (OUT_DIM / 256);   // 512
        gemm_kernel<<<grid, 512, 0, stream>>>(xbf, wbf, wscale, out);
    }
    ln_kernel<<<N_ROWS, 256, 0, stream>>>(out, bias);
}